// Round 2
// baseline (288.133 us; speedup 1.0000x reference)
//
#include <hip/hip_runtime.h>

#define T_TOTAL 4194304
#define BLK 1024
#define CHUNK (BLK * 4)          // 4096 elements per block
#define NB (T_TOTAL / CHUNK)     // 1024 blocks / tickets
#define NWAVE (BLK / 64)         // 16 waves per block
#define SCOPE __HIP_MEMORY_SCOPE_AGENT

// -------- helpers --------
__device__ __forceinline__ void f4_to_arr(float4 v, float* a) {
    a[0] = v.x; a[1] = v.y; a[2] = v.z; a[3] = v.w;
}

// a[i] = terminals*min(1,ratio), d[i] = min(1,ratio)*(rew + term*nv - val)
__device__ __forceinline__ void compute_ad(
    size_t f4,
    const float* __restrict__ lp, const float* __restrict__ olp,
    const float* __restrict__ val, const float* __restrict__ nval,
    const float* __restrict__ rew, const float* __restrict__ ter,
    float* a, float* d)
{
    float L[4], O[4], V[4], N[4], R[4], Tm[4];
    f4_to_arr(((const float4*)lp)[f4],  L);
    f4_to_arr(((const float4*)olp)[f4], O);
    f4_to_arr(((const float4*)val)[f4], V);
    f4_to_arr(((const float4*)nval)[f4],N);
    f4_to_arr(((const float4*)rew)[f4], R);
    f4_to_arr(((const float4*)ter)[f4], Tm);
#pragma unroll
    for (int i = 0; i < 4; ++i) {
        float ratio = __expf(L[i] - O[i]);
        float rho   = fminf(1.0f, ratio);
        a[i] = Tm[i] * rho;
        d[i] = rho * (R[i] + Tm[i] * N[i] - V[i]);
    }
}

// ws layout (uint words): [0]=ticket counter, [1]=done counter, [2..3]=acc(double),
// [4 .. 4+NB)=flags, then gA[NB], gD[NB], gV[NB] (floats)
__global__ __launch_bounds__(BLK) void k_init(unsigned* __restrict__ w) {
    for (int i = threadIdx.x; i < 4 + NB; i += BLK) w[i] = 0u;
}

__global__ __launch_bounds__(BLK) void k_vtrace(
    const float* __restrict__ lp, const float* __restrict__ olp,
    const float* __restrict__ val, const float* __restrict__ nval,
    const float* __restrict__ rew, const float* __restrict__ ter,
    unsigned* __restrict__ counter, unsigned* __restrict__ done,
    double* __restrict__ acc, unsigned* __restrict__ flags,
    float* __restrict__ gA, float* __restrict__ gD, float* __restrict__ gV,
    float* __restrict__ out)
{
    __shared__ float wA[NWAVE], wD[NWAVE], rsum[NWAVE];
    __shared__ float sv[CHUNK];
    __shared__ unsigned sTicket;
    __shared__ float sVin;

    const int t = threadIdx.x;
    const int lane = t & 63;
    const int w = t >> 6;

    if (t == 0) sTicket = atomicAdd(counter, 1u);
    __syncthreads();                                   // barrier 1
    const unsigned m = sTicket;                        // ticket 0 = rightmost chunk
    const int c = NB - 1 - (int)m;                     // chunk index (element order)
    const size_t f4 = (size_t)c * (CHUNK / 4) + t;

    float a[4], d[4];
    compute_ad(f4, lp, olp, val, nval, rew, ter, a, d);

    // per-thread segment transform: v_left = A*v_right + D (elements applied i=3..0)
    float A = 1.0f, D = 0.0f;
#pragma unroll
    for (int i = 0; i < 4; ++i) { D = fmaf(A, d[i], D); A *= a[i]; }

    // wave inclusive suffix scan (thread order: higher lane = applied earlier)
    float iA = A, iD = D;
#pragma unroll
    for (int s = 1; s < 64; s <<= 1) {
        float oA = __shfl_down(iA, s);
        float oD = __shfl_down(iD, s);
        if (lane + s < 64) { iD = fmaf(iA, oD, iD); iA *= oA; }
    }
    if (lane == 0) { wA[w] = iA; wD[w] = iD; }         // wave totals
    __syncthreads();                                   // barrier 2

    // suffix over later waves: S_w = W_{w+1} ∘ ... ∘ W_{15}
    float SA = 1.0f, SD = 0.0f;
    for (int j = w + 1; j < NWAVE; ++j) { SD = fmaf(SA, wD[j], SD); SA *= wA[j]; }

    // exclusive-within-wave (lanes l+1..63), then compose with wave suffix
    float eA = __shfl_down(iA, 1);
    float eD = __shfl_down(iD, 1);
    if (lane == 63) { eA = 1.0f; eD = 0.0f; }
    const float EA = eA * SA;
    const float ED = fmaf(eA, SD, eD);

    // thread 0 publishes block aggregate ASAP (lookback never blocks on this block)
    if (t == 0) {
        const float BA = iA * SA;
        const float BD = fmaf(iA, SD, iD);
        if (m == 0) {
            __hip_atomic_store(&gV[0], BD, __ATOMIC_RELAXED, SCOPE);
            __hip_atomic_store(&flags[0], 2u, __ATOMIC_RELEASE, SCOPE);
        } else {
            __hip_atomic_store(&gA[m], BA, __ATOMIC_RELAXED, SCOPE);
            __hip_atomic_store(&gD[m], BD, __ATOMIC_RELAXED, SCOPE);
            __hip_atomic_store(&flags[m], 1u, __ATOMIC_RELEASE, SCOPE);
        }
    }

    // wave 0: decoupled lookback (64 predecessors per probe)
    if (w == 0) {
        float vin = 0.0f;
        if (m > 0) {
            float GA = 1.0f, GD = 0.0f;   // consumed transforms (tickets (base, m-1])
            int base = (int)m - 1;
            for (;;) {
                const int tw = base - 63 + lane;
                unsigned fl;
                float Aw = 1.0f, Dw = 0.0f, Vw = 0.0f;
                if (tw >= 0) {
                    fl = __hip_atomic_load(&flags[tw], __ATOMIC_ACQUIRE, SCOPE);
                    if (fl >= 1u) {
                        Aw = __hip_atomic_load(&gA[tw], __ATOMIC_RELAXED, SCOPE);
                        Dw = __hip_atomic_load(&gD[tw], __ATOMIC_RELAXED, SCOPE);
                        if (fl == 2u) Vw = __hip_atomic_load(&gV[tw], __ATOMIC_RELAXED, SCOPE);
                    }
                } else fl = 1u;  // synthetic identity aggregate below ticket 0
                const unsigned long long ready = __ballot(fl >= 1u);
                const unsigned long long pref  = __ballot(fl == 2u);
                if (pref) {
                    const int lp = 63 - __clzll(pref);   // most-recent prefix in window
                    const unsigned long long need =
                        (lp == 63) ? 0ULL : (~0ULL << (lp + 1));
                    if ((ready & need) == need) {
                        float CA = 1.0f, CD = 0.0f;      // compose lanes 63..lp+1
                        for (int l = 63; l > lp; --l) {
                            const float Al = __shfl(Aw, l);
                            const float Dl = __shfl(Dw, l);
                            CD = fmaf(CA, Dl, CD);
                            CA *= Al;
                        }
                        const float vlp = __shfl(Vw, lp);
                        vin = fmaf(GA, fmaf(CA, vlp, CD), GD);
                        break;
                    }
                } else if (ready == ~0ULL) {             // whole window is aggregates
                    float CA = 1.0f, CD = 0.0f;
                    for (int l = 63; l >= 0; --l) {
                        const float Al = __shfl(Aw, l);
                        const float Dl = __shfl(Dw, l);
                        CD = fmaf(CA, Dl, CD);
                        CA *= Al;
                    }
                    GD = fmaf(GA, CD, GD);
                    GA *= CA;
                    base -= 64;
                    continue;
                }
                __builtin_amdgcn_s_sleep(1);
            }
            if (lane == 0) {  // publish inclusive prefix (carry for ticket m+1)
                const float BA = iA * SA;                // lane0 of wave0 == thread 0
                const float BD = fmaf(iA, SD, iD);
                const float vout = fmaf(BA, vin, BD);
                __hip_atomic_store(&gV[m], vout, __ATOMIC_RELAXED, SCOPE);
                __hip_atomic_store(&flags[m], 2u, __ATOMIC_RELEASE, SCOPE);
            }
        }
        if (lane == 0) sVin = vin;
    }
    __syncthreads();                                   // barrier 3
    const float vin = sVin;

    // per-thread incoming carry, then serial 4-element recurrence (ys = v)
    float v = fmaf(EA, vin, ED);
    float o[4];
#pragma unroll
    for (int i = 3; i >= 0; --i) { v = fmaf(a[i], v, d[i]); o[i] = v; }
    float ss = o[0]*o[0] + o[1]*o[1] + o[2]*o[2] + o[3]*o[3];

    // stage in LDS (vector write), coalesced scalar stores (out+1 misaligned for f4)
    ((float4*)sv)[t] = make_float4(o[0], o[1], o[2], o[3]);
    __syncthreads();                                   // barrier 4
    const size_t obase = 1 + (size_t)c * CHUNK;
#pragma unroll
    for (int k = 0; k < 4; ++k) out[obase + t + k * BLK] = sv[t + k * BLK];

    // loss: wave butterfly reduce -> LDS -> one atomic per block
#pragma unroll
    for (int s = 32; s > 0; s >>= 1) ss += __shfl_xor(ss, s);
    if (lane == 0) rsum[w] = ss;
    __syncthreads();                                   // barrier 5
    if (t == 0) {
        float bs = 0.0f;
        for (int j = 0; j < NWAVE; ++j) bs += rsum[j];
        atomicAdd(acc, (double)bs);
        __threadfence();
        const unsigned old = atomicAdd(done, 1u);
        if (old == NB - 1) {   // last block finalizes the loss
            const double av = __hip_atomic_load(acc, __ATOMIC_ACQUIRE, SCOPE);
            out[0] = (float)(av * (1.0 / (double)T_TOTAL));
        }
    }
}

extern "C" void kernel_launch(void* const* d_in, const int* in_sizes, int n_in,
                              void* d_out, int out_size, void* d_ws, size_t ws_size,
                              hipStream_t stream) {
    const float* lp   = (const float*)d_in[0];
    const float* olp  = (const float*)d_in[1];
    const float* val  = (const float*)d_in[2];
    const float* nval = (const float*)d_in[3];
    const float* rew  = (const float*)d_in[4];
    const float* ter  = (const float*)d_in[5];
    float* out = (float*)d_out;

    unsigned* wsw    = (unsigned*)d_ws;
    unsigned* counter = wsw + 0;
    unsigned* done    = wsw + 1;
    double*   acc     = (double*)(wsw + 2);
    unsigned* flags   = wsw + 4;
    float*    gA      = (float*)(wsw + 4 + NB);
    float*    gD      = gA + NB;
    float*    gV      = gD + NB;

    k_init<<<1, BLK, 0, stream>>>(wsw);
    k_vtrace<<<NB, BLK, 0, stream>>>(lp, olp, val, nval, rew, ter,
                                     counter, done, acc, flags, gA, gD, gV, out);
}